// Round 1
// baseline (620.057 us; speedup 1.0000x reference)
//
#include <hip/hip_runtime.h>
#include <hip/hip_bf16.h>
#include <cstdint>

// Sizes (compile-time constants for this problem)
// B=8 N=64 L=256 H=768 E=1536 NH=12 HD=128 HL=1024 C=42
// rows = B*N = 512

// ---------------- gather: cat[bn][0:768]=hidden[bn][i0], [768:1536]=hidden[bn][i1]
__global__ void gather_kernel(const float* __restrict__ hidden, const int* __restrict__ inds,
                              float* __restrict__ cat) {
  int bn = blockIdx.x;                       // 0..511 = b*64+n
  int i0 = inds[bn * 2 + 0], i1 = inds[bn * 2 + 1];
  const float* r0 = hidden + ((size_t)bn * 256 + i0) * 768;
  const float* r1 = hidden + ((size_t)bn * 256 + i1) * 768;
  float* c = cat + (size_t)bn * 1536;
  for (int i = threadIdx.x; i < 768; i += 256) {
    c[i] = r0[i];
    c[768 + i] = r1[i];
  }
}

// ---------------- fp32 tiled GEMM: C[MxN] = A[MxK] @ B (+bias)
// TRANSB=false: C[i,j] = sum_k A[i,k]*Bm[k*N+j]
// TRANSB=true : C[i,j] = sum_k A[i,k]*Bm[j*K+k]   (Bm row-major [N,K])
template <bool TRANSB, bool BIAS>
__global__ __launch_bounds__(256) void gemm_kernel(
    const float* __restrict__ A, const float* __restrict__ Bm,
    const float* __restrict__ bias, float* __restrict__ C,
    int M, int N, int K) {
  __shared__ float As[32][64];   // As[k][i]
  __shared__ float Bs[32][64];   // Bs[k][j]
  const int tid = threadIdx.x;
  const int i0 = blockIdx.y * 64, j0 = blockIdx.x * 64;
  const int tr = tid >> 4, tc = tid & 15;
  float acc[4][4] = {};
  for (int k0 = 0; k0 < K; k0 += 32) {
#pragma unroll
    for (int l = 0; l < 2; ++l) {           // A tile 64x32
      int idx = tid * 2 + l;                // 0..511 float4s
      int r = idx >> 3, kq = idx & 7;
      float4 av = *(const float4*)(A + (size_t)(i0 + r) * K + k0 + kq * 4);
      As[kq * 4 + 0][r] = av.x; As[kq * 4 + 1][r] = av.y;
      As[kq * 4 + 2][r] = av.z; As[kq * 4 + 3][r] = av.w;
    }
    if (!TRANSB) {
#pragma unroll
      for (int l = 0; l < 2; ++l) {         // B tile 32x64 (row-major slice)
        int idx = tid * 2 + l;
        int kk = idx >> 4, j4 = (idx & 15) * 4;
        float4 bv = *(const float4*)(Bm + (size_t)(k0 + kk) * N + j0 + j4);
        Bs[kk][j4 + 0] = bv.x; Bs[kk][j4 + 1] = bv.y;
        Bs[kk][j4 + 2] = bv.z; Bs[kk][j4 + 3] = bv.w;
      }
    } else {
#pragma unroll
      for (int l = 0; l < 2; ++l) {         // rows of Bm (N,K): transpose into Bs
        int idx = tid * 2 + l;
        int j = idx >> 3, kq = idx & 7;
        float4 bv = *(const float4*)(Bm + (size_t)(j0 + j) * K + k0 + kq * 4);
        Bs[kq * 4 + 0][j] = bv.x; Bs[kq * 4 + 1][j] = bv.y;
        Bs[kq * 4 + 2][j] = bv.z; Bs[kq * 4 + 3][j] = bv.w;
      }
    }
    __syncthreads();
#pragma unroll
    for (int kk = 0; kk < 32; ++kk) {
      float a[4], b[4];
#pragma unroll
      for (int x = 0; x < 4; ++x) a[x] = As[kk][tr * 4 + x];
#pragma unroll
      for (int x = 0; x < 4; ++x) b[x] = Bs[kk][tc * 4 + x];
#pragma unroll
      for (int ii = 0; ii < 4; ++ii)
#pragma unroll
        for (int jj = 0; jj < 4; ++jj) acc[ii][jj] += a[ii] * b[jj];
    }
    __syncthreads();
  }
#pragma unroll
  for (int ii = 0; ii < 4; ++ii) {
    float4 r;
    r.x = acc[ii][0]; r.y = acc[ii][1]; r.z = acc[ii][2]; r.w = acc[ii][3];
    if (BIAS) {
      r.x += bias[j0 + tc * 4 + 0]; r.y += bias[j0 + tc * 4 + 1];
      r.z += bias[j0 + tc * 4 + 2]; r.w += bias[j0 + tc * 4 + 3];
    }
    *(float4*)(C + (size_t)(i0 + tr * 4 + ii) * N + j0 + tc * 4) = r;
  }
}

// ---------------- fused attention: one block per (b,h); 96 blocks
// q,k,v are (512,1536) with head offset h*128. scores=q.k^T/sqrt(128), softmax over m, o=attn@v
__global__ __launch_bounds__(256) void attn_kernel(
    const float* __restrict__ q, const float* __restrict__ k,
    const float* __restrict__ v, float* __restrict__ o) {
  __shared__ float bufA[64 * 128];  // q then v; float4-column rotated by row
  __shared__ float bufB[64 * 128];  // k; then attn overlay with pitch 68
  const int b = blockIdx.x / 12, h = blockIdx.x % 12;
  const int tid = threadIdx.x;
  const size_t base = (size_t)b * 64 * 1536 + (size_t)h * 128;
  // load q,k tiles (64x128) with swizzled store: element-block c4 -> (c4+row)&31
  for (int f = tid; f < 2048; f += 256) {
    int row = f >> 5, c4 = f & 31;
    int sc4 = (c4 + row) & 31;
    *(float4*)&bufA[row * 128 + sc4 * 4] = *(const float4*)(q + base + (size_t)row * 1536 + c4 * 4);
    *(float4*)&bufB[row * 128 + sc4 * 4] = *(const float4*)(k + base + (size_t)row * 1536 + c4 * 4);
  }
  __syncthreads();
  const int n = tid >> 2, mq = tid & 3;
  float sc[16];
#pragma unroll
  for (int mi = 0; mi < 16; ++mi) {
    int m = mq + mi * 4;
    float s = 0.f;
#pragma unroll 8
    for (int d4 = 0; d4 < 32; ++d4) {
      float4 qa = *(const float4*)&bufA[n * 128 + ((d4 + n) & 31) * 4];
      float4 kb = *(const float4*)&bufB[m * 128 + ((d4 + m) & 31) * 4];
      s += qa.x * kb.x + qa.y * kb.y + qa.z * kb.z + qa.w * kb.w;
    }
    sc[mi] = s * 0.08838834764831845f;  // 1/sqrt(128)
  }
  float mx = sc[0];
#pragma unroll
  for (int mi = 1; mi < 16; ++mi) mx = fmaxf(mx, sc[mi]);
  mx = fmaxf(mx, __shfl_xor(mx, 1));
  mx = fmaxf(mx, __shfl_xor(mx, 2));
  float sum = 0.f;
#pragma unroll
  for (int mi = 0; mi < 16; ++mi) { sc[mi] = __expf(sc[mi] - mx); sum += sc[mi]; }
  sum += __shfl_xor(sum, 1);
  sum += __shfl_xor(sum, 2);
  float inv = 1.f / sum;
  __syncthreads();  // all q/k LDS reads done
  // attn overlay into bufB (pitch 68), v into bufA (swizzled)
#pragma unroll
  for (int mi = 0; mi < 16; ++mi) bufB[n * 68 + mq + mi * 4] = sc[mi] * inv;
  for (int f = tid; f < 2048; f += 256) {
    int row = f >> 5, c4 = f & 31;
    int sc4 = (c4 + row) & 31;
    *(float4*)&bufA[row * 128 + sc4 * 4] = *(const float4*)(v + base + (size_t)row * 1536 + c4 * 4);
  }
  __syncthreads();
  // o[n][d]: thread (n, dq) covers float4 columns c4 = dq + 4*i4 (stride-4 -> conflict-free)
  const int dq = tid & 3;
  float accv[32];
#pragma unroll
  for (int i = 0; i < 32; ++i) accv[i] = 0.f;
  for (int m = 0; m < 64; ++m) {
    float a = bufB[n * 68 + m];
#pragma unroll
    for (int i4 = 0; i4 < 8; ++i4) {
      int c4 = dq + 4 * i4;
      float4 vv = *(const float4*)&bufA[m * 128 + ((c4 + m) & 31) * 4];
      accv[i4 * 4 + 0] += a * vv.x; accv[i4 * 4 + 1] += a * vv.y;
      accv[i4 * 4 + 2] += a * vv.z; accv[i4 * 4 + 3] += a * vv.w;
    }
  }
#pragma unroll
  for (int i4 = 0; i4 < 8; ++i4) {
    int c4 = dq + 4 * i4;
    float4 r = make_float4(accv[i4 * 4 + 0], accv[i4 * 4 + 1], accv[i4 * 4 + 2], accv[i4 * 4 + 3]);
    *(float4*)(o + base + (size_t)n * 1536 + c4 * 4) = r;
  }
}

// ---------------- avg[b,e] = (1/64) sum_n attn_out[b,n,e]*cat[b,n,e]
__global__ void avg_kernel(const float* __restrict__ attn_out, const float* __restrict__ cat,
                           float* __restrict__ avg) {
  int idx = blockIdx.x * 256 + threadIdx.x;  // < 12288
  int b = idx / 1536, e = idx - b * 1536;
  const float* ao = attn_out + (size_t)b * 64 * 1536 + e;
  const float* ct = cat + (size_t)b * 64 * 1536 + e;
  float s = 0.f;
#pragma unroll 8
  for (int n2 = 0; n2 < 64; ++n2) s += ao[n2 * 1536] * ct[n2 * 1536];
  avg[idx] = s * (1.0f / 64.0f);
}

// ---------------- xg[d][r][j] = avg[r] . Wih_d[j] + bih_d[j] + bhh_d[j]
// one wave per output; 65536 waves
__global__ __launch_bounds__(256) void lstm_pre_kernel(
    const float* __restrict__ avg,
    const float* __restrict__ Wih_f, const float* __restrict__ bih_f, const float* __restrict__ bhh_f,
    const float* __restrict__ Wih_b, const float* __restrict__ bih_b, const float* __restrict__ bhh_b,
    float* __restrict__ xg) {
  int g = blockIdx.x * 4 + (threadIdx.x >> 6);
  int lane = threadIdx.x & 63;
  int d = g >> 15, rem = g & 32767, r = rem >> 12, j = rem & 4095;
  const float* W = d ? Wih_b : Wih_f;
  const float4* wrow = (const float4*)(W + (size_t)j * 1536);
  const float4* xv = (const float4*)(avg + (size_t)r * 1536);
  float s = 0.f;
#pragma unroll
  for (int t = 0; t < 6; ++t) {
    int k4 = lane + t * 64;
    float4 w = wrow[k4];
    float4 x = xv[k4];
    s += w.x * x.x + w.y * x.y + w.z * x.z + w.w * x.w;
  }
#pragma unroll
  for (int off = 32; off; off >>= 1) s += __shfl_xor(s, off);
  if (lane == 0) {
    float bias = d ? (bih_b[j] + bhh_b[j]) : (bih_f[j] + bhh_f[j]);
    xg[g] = s + bias;
  }
}

// ---------------- one LSTM time step, both directions. 256 blocks:
// block = d*128 + jchunk (8 j's). h double-buffered across steps (cross-block race);
// c is block-private (each j owned by exactly one block).
__global__ __launch_bounds__(256) void lstm_step_kernel(
    const float* __restrict__ Whh_f, const float* __restrict__ Whh_b,
    const float* __restrict__ xg, float* __restrict__ hstate, float* __restrict__ cstate,
    float* __restrict__ hout, int s) {
  __shared__ float hs[1024];
  __shared__ float gsm[4][8];
  const int d = blockIdx.x >> 7;
  const int j0 = (blockIdx.x & 127) * 8;
  const int tid = threadIdx.x, wave = tid >> 6, lane = tid & 63;
  const float* Whh = d ? Whh_b : Whh_f;
  const float* hread = hstate + ((size_t)(s & 1) * 2 + d) * 1024;
  float* hwrite = hstate + ((size_t)((s + 1) & 1) * 2 + d) * 1024;
  float* c = cstate + (size_t)d * 1024;
  const int r = d ? (7 - s) : s;  // input row / output row
  if (s == 0) {
    for (int i = tid; i < 1024; i += 256) hs[i] = 0.f;
  } else {
    for (int i = tid; i < 1024; i += 256) hs[i] = hread[i];
  }
  __syncthreads();
  const float* xgr = xg + ((size_t)d * 8 + r) * 4096;
  for (int jj = 0; jj < 8; ++jj) {
    const float4* wrow = (const float4*)(Whh + (size_t)(wave * 1024 + j0 + jj) * 1024);
    const float4* hv4 = (const float4*)hs;
    float sacc = 0.f;
#pragma unroll
    for (int t4 = 0; t4 < 4; ++t4) {
      int k4 = lane + t4 * 64;
      float4 w = wrow[k4];
      float4 hv = hv4[k4];
      sacc += w.x * hv.x + w.y * hv.y + w.z * hv.z + w.w * hv.w;
    }
#pragma unroll
    for (int off = 32; off; off >>= 1) sacc += __shfl_xor(sacc, off);
    if (lane == 0) gsm[wave][jj] = sacc;
  }
  __syncthreads();
  if (tid < 8) {
    int j = j0 + tid;
    float gi = gsm[0][tid] + xgr[j];
    float gf = gsm[1][tid] + xgr[1024 + j];
    float gg = gsm[2][tid] + xgr[2048 + j];
    float go = gsm[3][tid] + xgr[3072 + j];
    float iv = 1.f / (1.f + __expf(-gi));
    float fv = 1.f / (1.f + __expf(-gf));
    float ov = 1.f / (1.f + __expf(-go));
    float cold = (s == 0) ? 0.f : c[j];
    float cn = fv * cold + iv * tanhf(gg);
    float hn = ov * tanhf(cn);
    c[j] = cn;
    hwrite[j] = hn;
    hout[((size_t)d * 8 + r) * 1024 + j] = hn;
  }
}

// ---------------- logits = lstm_out @ out_w.T + out_b ; softmax over 42 classes
__global__ __launch_bounds__(256) void final_kernel(
    const float* __restrict__ hout, const float* __restrict__ out_w,
    const float* __restrict__ out_b, float* __restrict__ outp) {
  __shared__ float lo[2048];
  __shared__ float logits[64];
  const int s = blockIdx.x, tid = threadIdx.x;
  for (int i = tid; i < 1024; i += 256) {
    lo[i] = hout[(size_t)s * 1024 + i];           // hf[s]
    lo[1024 + i] = hout[(size_t)(8 + s) * 1024 + i];  // hb[s]
  }
  __syncthreads();
  const int wave = tid >> 6, lane = tid & 63;
  for (int cls = wave; cls < 42; cls += 4) {
    const float4* wr = (const float4*)(out_w + (size_t)cls * 2048);
    const float4* xr = (const float4*)lo;
    float acc = 0.f;
#pragma unroll
    for (int t = 0; t < 8; ++t) {
      int k4 = lane + t * 64;
      float4 w = wr[k4];
      float4 x = xr[k4];
      acc += w.x * x.x + w.y * x.y + w.z * x.z + w.w * x.w;
    }
#pragma unroll
    for (int off = 32; off; off >>= 1) acc += __shfl_xor(acc, off);
    if (lane == 0) logits[cls] = acc + out_b[cls];
  }
  __syncthreads();
  if (tid == 0) {
    float mx = -1e30f;
    for (int c2 = 0; c2 < 42; ++c2) mx = fmaxf(mx, logits[c2]);
    float sum = 0.f;
    for (int c2 = 0; c2 < 42; ++c2) {
      float e = __expf(logits[c2] - mx);
      logits[c2] = e;
      sum += e;
    }
    float inv = 1.f / sum;
    for (int c2 = 0; c2 < 42; ++c2) outp[s * 42 + c2] = logits[c2] * inv;
  }
}

extern "C" void kernel_launch(void* const* d_in, const int* in_sizes, int n_in,
                              void* d_out, int out_size, void* d_ws, size_t ws_size,
                              hipStream_t stream) {
  const float* hidden     = (const float*)d_in[0];
  const int*   inds       = (const int*)d_in[1];
  const float* Wkey       = (const float*)d_in[2];
  const float* Wque       = (const float*)d_in[3];
  const float* Wval       = (const float*)d_in[4];
  const float* in_proj_w  = (const float*)d_in[5];
  const float* in_proj_b  = (const float*)d_in[6];
  const float* out_proj_w = (const float*)d_in[7];
  const float* out_proj_b = (const float*)d_in[8];
  const float* Wih_f      = (const float*)d_in[9];
  const float* Whh_f      = (const float*)d_in[10];
  const float* bih_f      = (const float*)d_in[11];
  const float* bhh_f      = (const float*)d_in[12];
  const float* Wih_b      = (const float*)d_in[13];
  const float* Whh_b      = (const float*)d_in[14];
  const float* bih_b      = (const float*)d_in[15];
  const float* bhh_b      = (const float*)d_in[16];
  const float* out_w      = (const float*)d_in[17];
  const float* out_b      = (const float*)d_in[18];
  float* out = (float*)d_out;

  float* ws = (float*)d_ws;
  float* cat      = ws;                    // 512*1536
  float* keys     = cat + 786432;
  float* queries  = keys + 786432;
  float* values   = queries + 786432;
  float* qb       = values + 786432;
  float* kb       = qb + 786432;
  float* vb       = kb + 786432;
  float* ob       = vb + 786432;
  float* attn_out = ob + 786432;
  float* avg      = attn_out + 786432;     // 12288
  float* xg       = avg + 12288;           // 65536 : [d][r][4096]
  float* hstate   = xg + 65536;            // 4096  : [buf][d][1024]
  float* cstate   = hstate + 4096;         // 2048  : [d][1024]
  float* hout     = cstate + 2048;         // 16384 : [d][r][1024]

  gather_kernel<<<512, 256, 0, stream>>>(hidden, inds, cat);

  dim3 gg(24, 8);  // N/64, M/64
  gemm_kernel<false, false><<<gg, 256, 0, stream>>>(cat, Wkey, nullptr, keys, 512, 1536, 1536);
  gemm_kernel<false, false><<<gg, 256, 0, stream>>>(cat, Wque, nullptr, queries, 512, 1536, 1536);
  gemm_kernel<false, false><<<gg, 256, 0, stream>>>(cat, Wval, nullptr, values, 512, 1536, 1536);
  // q = keys@Wq.T+bq ; k = queries@Wk.T+bk ; v = values@Wv.T+bv
  gemm_kernel<true, true><<<gg, 256, 0, stream>>>(keys, in_proj_w, in_proj_b, qb, 512, 1536, 1536);
  gemm_kernel<true, true><<<gg, 256, 0, stream>>>(queries, in_proj_w + 1536 * 1536, in_proj_b + 1536, kb, 512, 1536, 1536);
  gemm_kernel<true, true><<<gg, 256, 0, stream>>>(values, in_proj_w + 2 * 1536 * 1536, in_proj_b + 2 * 1536, vb, 512, 1536, 1536);

  attn_kernel<<<96, 256, 0, stream>>>(qb, kb, vb, ob);

  gemm_kernel<true, true><<<gg, 256, 0, stream>>>(ob, out_proj_w, out_proj_b, attn_out, 512, 1536, 1536);

  avg_kernel<<<48, 256, 0, stream>>>(attn_out, cat, avg);

  lstm_pre_kernel<<<16384, 256, 0, stream>>>(avg, Wih_f, bih_f, bhh_f, Wih_b, bih_b, bhh_b, xg);

  for (int s = 0; s < 8; ++s)
    lstm_step_kernel<<<256, 256, 0, stream>>>(Whh_f, Whh_b, xg, hstate, cstate, hout, s);

  final_kernel<<<8, 256, 0, stream>>>(hout, out_w, out_b, out);
}

// Round 2
// 221.462 us; speedup vs baseline: 2.7998x; 2.7998x over previous
//
#include <hip/hip_runtime.h>
#include <hip/hip_bf16.h>
#include <cstdint>

// B=8 N=64 L=256 H=768 E=1536 NH=12 HD=128 HL=1024 C=42 ; rows = B*N = 512

typedef __attribute__((ext_vector_type(8))) short short8_t;
typedef __attribute__((ext_vector_type(4))) float f32x4_t;

// ---------------- gather: cat[bn][0:768]=hidden[bn][i0], [768:1536]=hidden[bn][i1]
// writes fp32 (for avg) and bf16 (GEMM A operand)
__global__ void gather_kernel(const float* __restrict__ hidden, const int* __restrict__ inds,
                              float* __restrict__ cat, __hip_bfloat16* __restrict__ cat16) {
  int bn = blockIdx.x;
  int i0 = inds[bn * 2 + 0], i1 = inds[bn * 2 + 1];
  const float* r0 = hidden + ((size_t)bn * 256 + i0) * 768;
  const float* r1 = hidden + ((size_t)bn * 256 + i1) * 768;
  float* c = cat + (size_t)bn * 1536;
  __hip_bfloat16* c16 = cat16 + (size_t)bn * 1536;
  for (int i = threadIdx.x; i < 768; i += 256) {
    float a = r0[i], b = r1[i];
    c[i] = a; c[768 + i] = b;
    c16[i] = __float2bfloat16(a); c16[768 + i] = __float2bfloat16(b);
  }
}

// ---------------- prep: Wt[z][n][k] = W_z[k][n] as bf16 (for TRANSB-style MFMA B operand)
__global__ __launch_bounds__(256) void transpose_cvt_kernel(
    const float* __restrict__ W0, const float* __restrict__ W1, const float* __restrict__ W2,
    __hip_bfloat16* __restrict__ out) {
  const float* W = blockIdx.z == 0 ? W0 : (blockIdx.z == 1 ? W1 : W2);
  __hip_bfloat16* O = out + (size_t)blockIdx.z * 1536 * 1536;
  __shared__ float tile[32][33];
  int n0 = blockIdx.x * 32, k0 = blockIdx.y * 32;
  int t = threadIdx.x, r = t >> 3, c4 = (t & 7) * 4;
  float4 v = *(const float4*)(W + (size_t)(k0 + r) * 1536 + n0 + c4);
  tile[r][c4] = v.x; tile[r][c4 + 1] = v.y; tile[r][c4 + 2] = v.z; tile[r][c4 + 3] = v.w;
  __syncthreads();
  union { ushort4 u; __hip_bfloat16 h[4]; } pk;
#pragma unroll
  for (int j = 0; j < 4; ++j) pk.h[j] = __float2bfloat16(tile[c4 + j][r]);
  *(ushort4*)(O + (size_t)(n0 + r) * 1536 + k0 + c4) = pk.u;
}

// ---------------- prep: elementwise fp32 -> bf16 (src size = n8*8)
__global__ void cvt_kernel(const float* __restrict__ src, __hip_bfloat16* __restrict__ dst) {
  int i = blockIdx.x * 256 + threadIdx.x;
  float4 a = ((const float4*)src)[2 * i], b = ((const float4*)src)[2 * i + 1];
  union { uint4 u; __hip_bfloat16 h[8]; } pk;
  pk.h[0] = __float2bfloat16(a.x); pk.h[1] = __float2bfloat16(a.y);
  pk.h[2] = __float2bfloat16(a.z); pk.h[3] = __float2bfloat16(a.w);
  pk.h[4] = __float2bfloat16(b.x); pk.h[5] = __float2bfloat16(b.y);
  pk.h[6] = __float2bfloat16(b.z); pk.h[7] = __float2bfloat16(b.w);
  *(uint4*)(dst + (size_t)i * 8) = pk.u;
}

// ---------------- bf16 MFMA GEMM: C[512,1536] = A[512,1536] @ Bm^T (+bias)
// A bf16 [M][K] k-major; Bm bf16 [N][K] k-major. 64x64 tile, BK=64, 4 waves (2x2),
// each wave 32x32 (2x2 frags of 16x16x32). LDS XOR-swizzle: byte ^= (row&7)<<4.
template <bool OUT_BF16, bool BIAS>
__global__ __launch_bounds__(256) void mfma_gemm(
    const __hip_bfloat16* __restrict__ A, long As,
    const __hip_bfloat16* __restrict__ Bm, long Bs,
    const float* __restrict__ bias, long biasS,
    void* __restrict__ Cp, long Cs) {
  constexpr int K = 1536, N = 1536;
  const int z = blockIdx.z;
  A += (size_t)z * As; Bm += (size_t)z * Bs;
  if (BIAS) bias += (size_t)z * biasS;
  __shared__ __align__(16) short Abuf[64 * 64];
  __shared__ __align__(16) short Bbuf[64 * 64];
  const int t = threadIdx.x;
  const int i0 = blockIdx.y * 64, j0 = blockIdx.x * 64;
  const int row = t >> 2, kq = t & 3;
  const int lane = t & 63, wave = t >> 6, wr = wave >> 1, wc = wave & 1;
  f32x4_t acc[2][2] = {};

  const char* Ag = (const char*)(A + (size_t)(i0 + row) * K) + kq * 32;
  const char* Bg = (const char*)(Bm + (size_t)(j0 + row) * K) + kq * 32;
  const int swz = (row & 7) << 4;
  char* Asw0 = (char*)Abuf + ((row * 128 + kq * 32) ^ swz);
  char* Asw1 = (char*)Abuf + ((row * 128 + kq * 32 + 16) ^ swz);
  char* Bsw0 = (char*)Bbuf + ((row * 128 + kq * 32) ^ swz);
  char* Bsw1 = (char*)Bbuf + ((row * 128 + kq * 32 + 16) ^ swz);

  for (int kb = 0; kb < K * 2; kb += 128) {  // 64 bf16 = 128 bytes per K-step
    uint4 a0 = *(const uint4*)(Ag + kb);
    uint4 a1 = *(const uint4*)(Ag + kb + 16);
    uint4 b0 = *(const uint4*)(Bg + kb);
    uint4 b1 = *(const uint4*)(Bg + kb + 16);
    __syncthreads();  // previous iter's frag reads done
    *(uint4*)Asw0 = a0; *(uint4*)Asw1 = a1;
    *(uint4*)Bsw0 = b0; *(uint4*)Bsw1 = b1;
    __syncthreads();
#pragma unroll
    for (int ks = 0; ks < 2; ++ks) {
      short8_t af[2], bfr[2];
#pragma unroll
      for (int mi = 0; mi < 2; ++mi) {
        int rr = wr * 32 + mi * 16 + (lane & 15);
        int off = (rr * 128 + ks * 64 + (lane >> 4) * 16) ^ ((rr & 7) << 4);
        af[mi] = *(const short8_t*)((const char*)Abuf + off);
      }
#pragma unroll
      for (int ni = 0; ni < 2; ++ni) {
        int rr = wc * 32 + ni * 16 + (lane & 15);
        int off = (rr * 128 + ks * 64 + (lane >> 4) * 16) ^ ((rr & 7) << 4);
        bfr[ni] = *(const short8_t*)((const char*)Bbuf + off);
      }
#pragma unroll
      for (int mi = 0; mi < 2; ++mi)
#pragma unroll
        for (int ni = 0; ni < 2; ++ni)
          acc[mi][ni] = __builtin_amdgcn_mfma_f32_16x16x32_bf16(af[mi], bfr[ni], acc[mi][ni], 0, 0, 0);
    }
  }
  // epilogue: C col=lane&15, row=(lane>>4)*4+r
#pragma unroll
  for (int mi = 0; mi < 2; ++mi)
#pragma unroll
    for (int ni = 0; ni < 2; ++ni) {
      int r0 = i0 + wr * 32 + mi * 16 + (lane >> 4) * 4;
      int col = j0 + wc * 32 + ni * 16 + (lane & 15);
      float bv = BIAS ? bias[col] : 0.f;
#pragma unroll
      for (int r = 0; r < 4; ++r) {
        float val = acc[mi][ni][r] + bv;
        if (OUT_BF16)
          ((__hip_bfloat16*)Cp)[(size_t)z * Cs + (size_t)(r0 + r) * N + col] = __float2bfloat16(val);
        else
          ((float*)Cp)[(size_t)z * Cs + (size_t)(r0 + r) * N + col] = val;
      }
    }
}

// ---------------- fused attention: one block per (b,h); 96 blocks; bf16 output
__global__ __launch_bounds__(256) void attn_kernel(
    const float* __restrict__ q, const float* __restrict__ k,
    const float* __restrict__ v, __hip_bfloat16* __restrict__ o) {
  __shared__ float bufA[64 * 128];
  __shared__ float bufB[64 * 128];
  const int b = blockIdx.x / 12, h = blockIdx.x % 12;
  const int tid = threadIdx.x;
  const size_t base = (size_t)b * 64 * 1536 + (size_t)h * 128;
  for (int f = tid; f < 2048; f += 256) {
    int row = f >> 5, c4 = f & 31;
    int sc4 = (c4 + row) & 31;
    *(float4*)&bufA[row * 128 + sc4 * 4] = *(const float4*)(q + base + (size_t)row * 1536 + c4 * 4);
    *(float4*)&bufB[row * 128 + sc4 * 4] = *(const float4*)(k + base + (size_t)row * 1536 + c4 * 4);
  }
  __syncthreads();
  const int n = tid >> 2, mq = tid & 3;
  float sc[16];
#pragma unroll
  for (int mi = 0; mi < 16; ++mi) {
    int m = mq + mi * 4;
    float s = 0.f;
#pragma unroll 8
    for (int d4 = 0; d4 < 32; ++d4) {
      float4 qa = *(const float4*)&bufA[n * 128 + ((d4 + n) & 31) * 4];
      float4 kb = *(const float4*)&bufB[m * 128 + ((d4 + m) & 31) * 4];
      s += qa.x * kb.x + qa.y * kb.y + qa.z * kb.z + qa.w * kb.w;
    }
    sc[mi] = s * 0.08838834764831845f;
  }
  float mx = sc[0];
#pragma unroll
  for (int mi = 1; mi < 16; ++mi) mx = fmaxf(mx, sc[mi]);
  mx = fmaxf(mx, __shfl_xor(mx, 1));
  mx = fmaxf(mx, __shfl_xor(mx, 2));
  float sum = 0.f;
#pragma unroll
  for (int mi = 0; mi < 16; ++mi) { sc[mi] = __expf(sc[mi] - mx); sum += sc[mi]; }
  sum += __shfl_xor(sum, 1);
  sum += __shfl_xor(sum, 2);
  float inv = 1.f / sum;
  __syncthreads();
#pragma unroll
  for (int mi = 0; mi < 16; ++mi) bufB[n * 68 + mq + mi * 4] = sc[mi] * inv;
  for (int f = tid; f < 2048; f += 256) {
    int row = f >> 5, c4 = f & 31;
    int sc4 = (c4 + row) & 31;
    *(float4*)&bufA[row * 128 + sc4 * 4] = *(const float4*)(v + base + (size_t)row * 1536 + c4 * 4);
  }
  __syncthreads();
  const int dq = tid & 3;
  float accv[32];
#pragma unroll
  for (int i = 0; i < 32; ++i) accv[i] = 0.f;
  for (int m = 0; m < 64; ++m) {
    float a = bufB[n * 68 + m];
#pragma unroll
    for (int i4 = 0; i4 < 8; ++i4) {
      int c4 = dq + 4 * i4;
      float4 vv = *(const float4*)&bufA[m * 128 + ((c4 + m) & 31) * 4];
      accv[i4 * 4 + 0] += a * vv.x; accv[i4 * 4 + 1] += a * vv.y;
      accv[i4 * 4 + 2] += a * vv.z; accv[i4 * 4 + 3] += a * vv.w;
    }
  }
#pragma unroll
  for (int i4 = 0; i4 < 8; ++i4) {
    int c4 = dq + 4 * i4;
    union { ushort4 u; __hip_bfloat16 h[4]; } pk;
    pk.h[0] = __float2bfloat16(accv[i4 * 4 + 0]); pk.h[1] = __float2bfloat16(accv[i4 * 4 + 1]);
    pk.h[2] = __float2bfloat16(accv[i4 * 4 + 2]); pk.h[3] = __float2bfloat16(accv[i4 * 4 + 3]);
    *(ushort4*)(o + base + (size_t)n * 1536 + c4 * 4) = pk.u;
  }
}

// ---------------- avg[b,e] = (1/64) sum_n attn_out[b,n,e]*cat[b,n,e]
__global__ void avg_kernel(const float* __restrict__ attn_out, const float* __restrict__ cat,
                           float* __restrict__ avg) {
  int idx = blockIdx.x * 256 + threadIdx.x;
  int b = idx / 1536, e = idx - b * 1536;
  const float* ao = attn_out + (size_t)b * 64 * 1536 + e;
  const float* ct = cat + (size_t)b * 64 * 1536 + e;
  float s = 0.f;
#pragma unroll 8
  for (int n2 = 0; n2 < 64; ++n2) s += ao[n2 * 1536] * ct[n2 * 1536];
  avg[idx] = s * (1.0f / 64.0f);
}

// ---------------- xg[d][r][j] = avg[r] . Wih_d[j] + bih_d[j] + bhh_d[j]
__global__ __launch_bounds__(256) void lstm_pre_kernel(
    const float* __restrict__ avg,
    const float* __restrict__ Wih_f, const float* __restrict__ bih_f, const float* __restrict__ bhh_f,
    const float* __restrict__ Wih_b, const float* __restrict__ bih_b, const float* __restrict__ bhh_b,
    float* __restrict__ xg) {
  int g = blockIdx.x * 4 + (threadIdx.x >> 6);
  int lane = threadIdx.x & 63;
  int d = g >> 15, rem = g & 32767, r = rem >> 12, j = rem & 4095;
  const float* W = d ? Wih_b : Wih_f;
  const float4* wrow = (const float4*)(W + (size_t)j * 1536);
  const float4* xv = (const float4*)(avg + (size_t)r * 1536);
  float s = 0.f;
#pragma unroll
  for (int t = 0; t < 6; ++t) {
    int k4 = lane + t * 64;
    float4 w = wrow[k4];
    float4 x = xv[k4];
    s += w.x * x.x + w.y * x.y + w.z * x.z + w.w * x.w;
  }
#pragma unroll
  for (int off = 32; off; off >>= 1) s += __shfl_xor(s, off);
  if (lane == 0) {
    float bias = d ? (bih_b[j] + bhh_b[j]) : (bih_f[j] + bhh_f[j]);
    xg[g] = s + bias;
  }
}

// ---------------- one LSTM time step (both dirs). h double-buffered across launches.
__global__ __launch_bounds__(256) void lstm_step_kernel(
    const float* __restrict__ Whh_f, const float* __restrict__ Whh_b,
    const float* __restrict__ xg, float* __restrict__ hstate, float* __restrict__ cstate,
    float* __restrict__ hout, int s) {
  __shared__ float hs[1024];
  __shared__ float gsm[4][8];
  const int d = blockIdx.x >> 7;
  const int j0 = (blockIdx.x & 127) * 8;
  const int tid = threadIdx.x, wave = tid >> 6, lane = tid & 63;
  const float* Whh = d ? Whh_b : Whh_f;
  const float* hread = hstate + ((size_t)(s & 1) * 2 + d) * 1024;
  float* hwrite = hstate + ((size_t)((s + 1) & 1) * 2 + d) * 1024;
  float* c = cstate + (size_t)d * 1024;
  const int r = d ? (7 - s) : s;
  if (s == 0) {
    for (int i = tid; i < 1024; i += 256) hs[i] = 0.f;
  } else {
    for (int i = tid; i < 1024; i += 256) hs[i] = hread[i];
  }
  __syncthreads();
  const float* xgr = xg + ((size_t)d * 8 + r) * 4096;
  for (int jj = 0; jj < 8; ++jj) {
    const float4* wrow = (const float4*)(Whh + (size_t)(wave * 1024 + j0 + jj) * 1024);
    const float4* hv4 = (const float4*)hs;
    float sacc = 0.f;
#pragma unroll
    for (int t4 = 0; t4 < 4; ++t4) {
      int k4 = lane + t4 * 64;
      float4 w = wrow[k4];
      float4 hv = hv4[k4];
      sacc += w.x * hv.x + w.y * hv.y + w.z * hv.z + w.w * hv.w;
    }
#pragma unroll
    for (int off = 32; off; off >>= 1) sacc += __shfl_xor(sacc, off);
    if (lane == 0) gsm[wave][jj] = sacc;
  }
  __syncthreads();
  if (tid < 8) {
    int j = j0 + tid;
    float gi = gsm[0][tid] + xgr[j];
    float gf = gsm[1][tid] + xgr[1024 + j];
    float gg = gsm[2][tid] + xgr[2048 + j];
    float go = gsm[3][tid] + xgr[3072 + j];
    float iv = 1.f / (1.f + __expf(-gi));
    float fv = 1.f / (1.f + __expf(-gf));
    float ov = 1.f / (1.f + __expf(-go));
    float cold = (s == 0) ? 0.f : c[j];
    float cn = fv * cold + iv * tanhf(gg);
    float hn = ov * tanhf(cn);
    c[j] = cn;
    hwrite[j] = hn;
    hout[((size_t)d * 8 + r) * 1024 + j] = hn;
  }
}

// ---------------- logits = lstm_out @ out_w.T + out_b ; softmax over 42 classes
__global__ __launch_bounds__(256) void final_kernel(
    const float* __restrict__ hout, const float* __restrict__ out_w,
    const float* __restrict__ out_b, float* __restrict__ outp) {
  __shared__ float lo[2048];
  __shared__ float logits[64];
  const int s = blockIdx.x, tid = threadIdx.x;
  for (int i = tid; i < 1024; i += 256) {
    lo[i] = hout[(size_t)s * 1024 + i];
    lo[1024 + i] = hout[(size_t)(8 + s) * 1024 + i];
  }
  __syncthreads();
  const int wave = tid >> 6, lane = tid & 63;
  for (int cls = wave; cls < 42; cls += 4) {
    const float4* wr = (const float4*)(out_w + (size_t)cls * 2048);
    const float4* xr = (const float4*)lo;
    float acc = 0.f;
#pragma unroll
    for (int t = 0; t < 8; ++t) {
      int k4 = lane + t * 64;
      float4 w = wr[k4];
      float4 x = xr[k4];
      acc += w.x * x.x + w.y * x.y + w.z * x.z + w.w * x.w;
    }
#pragma unroll
    for (int off = 32; off; off >>= 1) acc += __shfl_xor(acc, off);
    if (lane == 0) logits[cls] = acc + out_b[cls];
  }
  __syncthreads();
  if (tid == 0) {
    float mx = -1e30f;
    for (int c2 = 0; c2 < 42; ++c2) mx = fmaxf(mx, logits[c2]);
    float sum = 0.f;
    for (int c2 = 0; c2 < 42; ++c2) {
      float e = __expf(logits[c2] - mx);
      logits[c2] = e;
      sum += e;
    }
    float inv = 1.f / sum;
    for (int c2 = 0; c2 < 42; ++c2) outp[s * 42 + c2] = logits[c2] * inv;
  }
}

extern "C" void kernel_launch(void* const* d_in, const int* in_sizes, int n_in,
                              void* d_out, int out_size, void* d_ws, size_t ws_size,
                              hipStream_t stream) {
  const float* hidden     = (const float*)d_in[0];
  const int*   inds       = (const int*)d_in[1];
  const float* Wkey       = (const float*)d_in[2];
  const float* Wque       = (const float*)d_in[3];
  const float* Wval       = (const float*)d_in[4];
  const float* in_proj_w  = (const float*)d_in[5];
  const float* in_proj_b  = (const float*)d_in[6];
  const float* out_proj_w = (const float*)d_in[7];
  const float* out_proj_b = (const float*)d_in[8];
  const float* Wih_f      = (const float*)d_in[9];
  const float* Whh_f      = (const float*)d_in[10];
  const float* bih_f      = (const float*)d_in[11];
  const float* bhh_f      = (const float*)d_in[12];
  const float* Wih_b      = (const float*)d_in[13];
  const float* Whh_b      = (const float*)d_in[14];
  const float* bih_b      = (const float*)d_in[15];
  const float* bhh_b      = (const float*)d_in[16];
  const float* out_w      = (const float*)d_in[17];
  const float* out_b      = (const float*)d_in[18];
  float* out = (float*)d_out;

  float* ws = (float*)d_ws;
  float* cat      = ws;                    // 786432
  float* qkv2     = cat + 786432;          // 3*786432 (qb,kb,vb fp32)
  float* attn_out = qkv2 + 2359296;        // 786432
  float* avg      = attn_out + 786432;     // 12288
  float* xg       = avg + 12288;           // 65536
  float* hstate   = xg + 65536;            // 4096
  float* cstate   = hstate + 4096;         // 2048
  float* hout     = cstate + 2048;         // 16384
  __hip_bfloat16* b16 = (__hip_bfloat16*)(hout + 16384);
  __hip_bfloat16* cat16     = b16;                  // 786432
  __hip_bfloat16* Wt16      = cat16 + 786432;       // 3*1536*1536
  __hip_bfloat16* inproj16  = Wt16 + 7077888;       // 4608*1536
  __hip_bfloat16* outproj16 = inproj16 + 7077888;   // 1536*1536
  __hip_bfloat16* kqv1      = outproj16 + 2359296;  // 3*786432 (keys,queries,values bf16)
  __hip_bfloat16* ob16      = kqv1 + 2359296;       // 786432

  gather_kernel<<<512, 256, 0, stream>>>(hidden, inds, cat, cat16);
  transpose_cvt_kernel<<<dim3(48, 48, 3), 256, 0, stream>>>(Wkey, Wque, Wval, Wt16);
  cvt_kernel<<<3456, 256, 0, stream>>>(in_proj_w, inproj16);   // 4608*1536/8
  cvt_kernel<<<1152, 256, 0, stream>>>(out_proj_w, outproj16); // 1536*1536/8

  // stage 1: kqv1[z] = cat @ W_z   (bf16 out, no bias)
  mfma_gemm<true, false><<<dim3(24, 8, 3), 256, 0, stream>>>(
      cat16, 0, Wt16, 1536L * 1536, nullptr, 0, kqv1, 786432);
  // stage 2: qkv2[z] = kqv1[z] @ in_proj_w[z].T + b[z]  (fp32 out)
  mfma_gemm<false, true><<<dim3(24, 8, 3), 256, 0, stream>>>(
      kqv1, 786432, inproj16, 1536L * 1536, in_proj_b, 1536, qkv2, 786432);

  attn_kernel<<<96, 256, 0, stream>>>(qkv2, qkv2 + 786432, qkv2 + 2 * 786432, ob16);

  // out_proj: attn_out = ob @ out_proj_w.T + b (fp32 out)
  mfma_gemm<false, true><<<dim3(24, 8, 1), 256, 0, stream>>>(
      ob16, 0, outproj16, 0, out_proj_b, 0, attn_out, 0);

  avg_kernel<<<48, 256, 0, stream>>>(attn_out, cat, avg);

  lstm_pre_kernel<<<16384, 256, 0, stream>>>(avg, Wih_f, bih_f, bhh_f, Wih_b, bih_b, bhh_b, xg);

  for (int s = 0; s < 8; ++s)
    lstm_step_kernel<<<256, 256, 0, stream>>>(Whh_f, Whh_b, xg, hstate, cstate, hout, s);

  final_kernel<<<8, 256, 0, stream>>>(hout, out_w, out_b, out);
}

// Round 3
// 203.037 us; speedup vs baseline: 3.0539x; 1.0907x over previous
//
#include <hip/hip_runtime.h>
#include <hip/hip_bf16.h>
#include <cstdint>

// B=8 N=64 L=256 H=768 E=1536 NH=12 HD=128 HL=1024 C=42 ; rows = B*N = 512

typedef __attribute__((ext_vector_type(8))) short short8_t;
typedef __attribute__((ext_vector_type(4))) float f32x4_t;

// ---------------- gather: cat[bn][0:768]=hidden[bn][i0], [768:1536]=hidden[bn][i1]
__global__ void gather_kernel(const float* __restrict__ hidden, const int* __restrict__ inds,
                              float* __restrict__ cat, __hip_bfloat16* __restrict__ cat16) {
  int bn = blockIdx.x;
  int i0 = inds[bn * 2 + 0], i1 = inds[bn * 2 + 1];
  const float* r0 = hidden + ((size_t)bn * 256 + i0) * 768;
  const float* r1 = hidden + ((size_t)bn * 256 + i1) * 768;
  float* c = cat + (size_t)bn * 1536;
  __hip_bfloat16* c16 = cat16 + (size_t)bn * 1536;
  for (int i = threadIdx.x; i < 768; i += 256) {
    float a = r0[i], b = r1[i];
    c[i] = a; c[768 + i] = b;
    c16[i] = __float2bfloat16(a); c16[768 + i] = __float2bfloat16(b);
  }
}

// ---------------- prep: Wt[z][n][k] = W_z[k][n] as bf16
__global__ __launch_bounds__(256) void transpose_cvt_kernel(
    const float* __restrict__ W0, const float* __restrict__ W1, const float* __restrict__ W2,
    __hip_bfloat16* __restrict__ out) {
  const float* W = blockIdx.z == 0 ? W0 : (blockIdx.z == 1 ? W1 : W2);
  __hip_bfloat16* O = out + (size_t)blockIdx.z * 1536 * 1536;
  __shared__ float tile[32][33];
  int n0 = blockIdx.x * 32, k0 = blockIdx.y * 32;
  int t = threadIdx.x, r = t >> 3, c4 = (t & 7) * 4;
  float4 v = *(const float4*)(W + (size_t)(k0 + r) * 1536 + n0 + c4);
  tile[r][c4] = v.x; tile[r][c4 + 1] = v.y; tile[r][c4 + 2] = v.z; tile[r][c4 + 3] = v.w;
  __syncthreads();
  union { ushort4 u; __hip_bfloat16 h[4]; } pk;
#pragma unroll
  for (int j = 0; j < 4; ++j) pk.h[j] = __float2bfloat16(tile[c4 + j][r]);
  *(ushort4*)(O + (size_t)(n0 + r) * 1536 + k0 + c4) = pk.u;
}

// ---------------- fused prep: cvt in_proj (blocks 0..3455), cvt out_proj (3456..4607),
// Whh swizzle+cvt (4608..8703): whh16s[d][row][half][lane][8] = Whh_d[row][(half*8+e)*64+lane]
__global__ __launch_bounds__(256) void prep_kernel(
    const float* __restrict__ in_proj_w, const float* __restrict__ out_proj_w,
    const float* __restrict__ Whh_f, const float* __restrict__ Whh_b,
    __hip_bfloat16* __restrict__ inproj16, __hip_bfloat16* __restrict__ outproj16,
    __hip_bfloat16* __restrict__ whh16s) {
  int bid = blockIdx.x;
  if (bid < 4608) {
    const float* src; __hip_bfloat16* dst; int i;
    if (bid < 3456) { src = in_proj_w; dst = inproj16; i = bid * 256 + threadIdx.x; }
    else { src = out_proj_w; dst = outproj16; i = (bid - 3456) * 256 + threadIdx.x; }
    float4 a = ((const float4*)src)[2 * i], b = ((const float4*)src)[2 * i + 1];
    union { uint4 u; __hip_bfloat16 h[8]; } pk;
    pk.h[0] = __float2bfloat16(a.x); pk.h[1] = __float2bfloat16(a.y);
    pk.h[2] = __float2bfloat16(a.z); pk.h[3] = __float2bfloat16(a.w);
    pk.h[4] = __float2bfloat16(b.x); pk.h[5] = __float2bfloat16(b.y);
    pk.h[6] = __float2bfloat16(b.z); pk.h[7] = __float2bfloat16(b.w);
    *(uint4*)(dst + (size_t)i * 8) = pk.u;
  } else {
    int id = (bid - 4608) * 256 + threadIdx.x;        // 0..2^20-1
    int lane = id & 63, half = (id >> 6) & 1, row = (id >> 7) & 4095, d = id >> 19;
    const float* W = d ? Whh_b : Whh_f;
    const float* srcp = W + (size_t)row * 1024 + half * 512 + lane;
    union { uint4 u; __hip_bfloat16 h[8]; } pk;
#pragma unroll
    for (int e = 0; e < 8; ++e) pk.h[e] = __float2bfloat16(srcp[e * 64]);
    *(uint4*)(whh16s + (size_t)id * 8) = pk.u;
  }
}

// ---------------- bf16 MFMA GEMM (64x64 tile, BK=64, XOR-swizzled LDS)
template <bool OUT_BF16, bool BIAS>
__global__ __launch_bounds__(256) void mfma_gemm(
    const __hip_bfloat16* __restrict__ A, long As,
    const __hip_bfloat16* __restrict__ Bm, long Bs,
    const float* __restrict__ bias, long biasS,
    void* __restrict__ Cp, long Cs) {
  constexpr int K = 1536, N = 1536;
  const int z = blockIdx.z;
  A += (size_t)z * As; Bm += (size_t)z * Bs;
  if (BIAS) bias += (size_t)z * biasS;
  __shared__ __align__(16) short Abuf[64 * 64];
  __shared__ __align__(16) short Bbuf[64 * 64];
  const int t = threadIdx.x;
  const int i0 = blockIdx.y * 64, j0 = blockIdx.x * 64;
  const int row = t >> 2, kq = t & 3;
  const int lane = t & 63, wave = t >> 6, wr = wave >> 1, wc = wave & 1;
  f32x4_t acc[2][2] = {};

  const char* Ag = (const char*)(A + (size_t)(i0 + row) * K) + kq * 32;
  const char* Bg = (const char*)(Bm + (size_t)(j0 + row) * K) + kq * 32;
  const int swz = (row & 7) << 4;
  char* Asw0 = (char*)Abuf + ((row * 128 + kq * 32) ^ swz);
  char* Asw1 = (char*)Abuf + ((row * 128 + kq * 32 + 16) ^ swz);
  char* Bsw0 = (char*)Bbuf + ((row * 128 + kq * 32) ^ swz);
  char* Bsw1 = (char*)Bbuf + ((row * 128 + kq * 32 + 16) ^ swz);

  for (int kb = 0; kb < K * 2; kb += 128) {
    uint4 a0 = *(const uint4*)(Ag + kb);
    uint4 a1 = *(const uint4*)(Ag + kb + 16);
    uint4 b0 = *(const uint4*)(Bg + kb);
    uint4 b1 = *(const uint4*)(Bg + kb + 16);
    __syncthreads();
    *(uint4*)Asw0 = a0; *(uint4*)Asw1 = a1;
    *(uint4*)Bsw0 = b0; *(uint4*)Bsw1 = b1;
    __syncthreads();
#pragma unroll
    for (int ks = 0; ks < 2; ++ks) {
      short8_t af[2], bfr[2];
#pragma unroll
      for (int mi = 0; mi < 2; ++mi) {
        int rr = wr * 32 + mi * 16 + (lane & 15);
        int off = (rr * 128 + ks * 64 + (lane >> 4) * 16) ^ ((rr & 7) << 4);
        af[mi] = *(const short8_t*)((const char*)Abuf + off);
      }
#pragma unroll
      for (int ni = 0; ni < 2; ++ni) {
        int rr = wc * 32 + ni * 16 + (lane & 15);
        int off = (rr * 128 + ks * 64 + (lane >> 4) * 16) ^ ((rr & 7) << 4);
        bfr[ni] = *(const short8_t*)((const char*)Bbuf + off);
      }
#pragma unroll
      for (int mi = 0; mi < 2; ++mi)
#pragma unroll
        for (int ni = 0; ni < 2; ++ni)
          acc[mi][ni] = __builtin_amdgcn_mfma_f32_16x16x32_bf16(af[mi], bfr[ni], acc[mi][ni], 0, 0, 0);
    }
  }
#pragma unroll
  for (int mi = 0; mi < 2; ++mi)
#pragma unroll
    for (int ni = 0; ni < 2; ++ni) {
      int r0 = i0 + wr * 32 + mi * 16 + (lane >> 4) * 4;
      int col = j0 + wc * 32 + ni * 16 + (lane & 15);
      float bv = BIAS ? bias[col] : 0.f;
#pragma unroll
      for (int r = 0; r < 4; ++r) {
        float val = acc[mi][ni][r] + bv;
        if (OUT_BF16)
          ((__hip_bfloat16*)Cp)[(size_t)z * Cs + (size_t)(r0 + r) * N + col] = __float2bfloat16(val);
        else
          ((float*)Cp)[(size_t)z * Cs + (size_t)(r0 + r) * N + col] = val;
      }
    }
}

// ---------------- fused attention: one block per (b,h); 96 blocks; bf16 output
__global__ __launch_bounds__(256) void attn_kernel(
    const float* __restrict__ q, const float* __restrict__ k,
    const float* __restrict__ v, __hip_bfloat16* __restrict__ o) {
  __shared__ float bufA[64 * 128];
  __shared__ float bufB[64 * 128];
  const int b = blockIdx.x / 12, h = blockIdx.x % 12;
  const int tid = threadIdx.x;
  const size_t base = (size_t)b * 64 * 1536 + (size_t)h * 128;
  for (int f = tid; f < 2048; f += 256) {
    int row = f >> 5, c4 = f & 31;
    int sc4 = (c4 + row) & 31;
    *(float4*)&bufA[row * 128 + sc4 * 4] = *(const float4*)(q + base + (size_t)row * 1536 + c4 * 4);
    *(float4*)&bufB[row * 128 + sc4 * 4] = *(const float4*)(k + base + (size_t)row * 1536 + c4 * 4);
  }
  __syncthreads();
  const int n = tid >> 2, mq = tid & 3;
  float sc[16];
#pragma unroll
  for (int mi = 0; mi < 16; ++mi) {
    int m = mq + mi * 4;
    float s = 0.f;
#pragma unroll 8
    for (int d4 = 0; d4 < 32; ++d4) {
      float4 qa = *(const float4*)&bufA[n * 128 + ((d4 + n) & 31) * 4];
      float4 kb = *(const float4*)&bufB[m * 128 + ((d4 + m) & 31) * 4];
      s += qa.x * kb.x + qa.y * kb.y + qa.z * kb.z + qa.w * kb.w;
    }
    sc[mi] = s * 0.08838834764831845f;
  }
  float mx = sc[0];
#pragma unroll
  for (int mi = 1; mi < 16; ++mi) mx = fmaxf(mx, sc[mi]);
  mx = fmaxf(mx, __shfl_xor(mx, 1));
  mx = fmaxf(mx, __shfl_xor(mx, 2));
  float sum = 0.f;
#pragma unroll
  for (int mi = 0; mi < 16; ++mi) { sc[mi] = __expf(sc[mi] - mx); sum += sc[mi]; }
  sum += __shfl_xor(sum, 1);
  sum += __shfl_xor(sum, 2);
  float inv = 1.f / sum;
  __syncthreads();
#pragma unroll
  for (int mi = 0; mi < 16; ++mi) bufB[n * 68 + mq + mi * 4] = sc[mi] * inv;
  for (int f = tid; f < 2048; f += 256) {
    int row = f >> 5, c4 = f & 31;
    int sc4 = (c4 + row) & 31;
    *(float4*)&bufA[row * 128 + sc4 * 4] = *(const float4*)(v + base + (size_t)row * 1536 + c4 * 4);
  }
  __syncthreads();
  const int dq = tid & 3;
  float accv[32];
#pragma unroll
  for (int i = 0; i < 32; ++i) accv[i] = 0.f;
  for (int m = 0; m < 64; ++m) {
    float a = bufB[n * 68 + m];
#pragma unroll
    for (int i4 = 0; i4 < 8; ++i4) {
      int c4 = dq + 4 * i4;
      float4 vv = *(const float4*)&bufA[m * 128 + ((c4 + m) & 31) * 4];
      accv[i4 * 4 + 0] += a * vv.x; accv[i4 * 4 + 1] += a * vv.y;
      accv[i4 * 4 + 2] += a * vv.z; accv[i4 * 4 + 3] += a * vv.w;
    }
  }
#pragma unroll
  for (int i4 = 0; i4 < 8; ++i4) {
    int c4 = dq + 4 * i4;
    union { ushort4 u; __hip_bfloat16 h[4]; } pk;
    pk.h[0] = __float2bfloat16(accv[i4 * 4 + 0]); pk.h[1] = __float2bfloat16(accv[i4 * 4 + 1]);
    pk.h[2] = __float2bfloat16(accv[i4 * 4 + 2]); pk.h[3] = __float2bfloat16(accv[i4 * 4 + 3]);
    *(ushort4*)(o + base + (size_t)n * 1536 + c4 * 4) = pk.u;
  }
}

// ---------------- avg[b,e] = (1/64) sum_n attn_out[b,n,e]*cat[b,n,e]
__global__ void avg_kernel(const float* __restrict__ attn_out, const float* __restrict__ cat,
                           float* __restrict__ avg) {
  int idx = blockIdx.x * 256 + threadIdx.x;
  int b = idx / 1536, e = idx - b * 1536;
  const float* ao = attn_out + (size_t)b * 64 * 1536 + e;
  const float* ct = cat + (size_t)b * 64 * 1536 + e;
  float s = 0.f;
#pragma unroll 8
  for (int n2 = 0; n2 < 64; ++n2) s += ao[n2 * 1536] * ct[n2 * 1536];
  avg[idx] = s * (1.0f / 64.0f);
}

// ---------------- lstm_pre2: wave per (d,j) row; computes all 8 r's with one row read.
// xg[d][r][j] = avg[r] . Wih_d[j] + bih_d[j] + bhh_d[j]
__global__ __launch_bounds__(256) void lstm_pre2_kernel(
    const float* __restrict__ avg,
    const float* __restrict__ Wih_f, const float* __restrict__ bih_f, const float* __restrict__ bhh_f,
    const float* __restrict__ Wih_b, const float* __restrict__ bih_b, const float* __restrict__ bhh_b,
    float* __restrict__ xg) {
  int g = blockIdx.x * 4 + (threadIdx.x >> 6);   // 8192 waves
  int lane = threadIdx.x & 63;
  int d = g >> 12, j = g & 4095;
  const float* W = d ? Wih_b : Wih_f;
  const float4* wrow = (const float4*)(W + (size_t)j * 1536);
  float4 w[6];
#pragma unroll
  for (int c = 0; c < 6; ++c) w[c] = wrow[c * 64 + lane];
  float s[8] = {};
#pragma unroll
  for (int r = 0; r < 8; ++r) {
    const float4* av = (const float4*)(avg + (size_t)r * 1536);
#pragma unroll
    for (int c = 0; c < 6; ++c) {
      float4 x = av[c * 64 + lane];
      s[r] += w[c].x * x.x + w[c].y * x.y + w[c].z * x.z + w[c].w * x.w;
    }
  }
#pragma unroll
  for (int r = 0; r < 8; ++r)
#pragma unroll
    for (int off = 32; off; off >>= 1) s[r] += __shfl_xor(s[r], off);
  if (lane == 0) {
    float bias = d ? (bih_b[j] + bhh_b[j]) : (bih_f[j] + bhh_f[j]);
#pragma unroll
    for (int r = 0; r < 8; ++r) xg[((size_t)d * 8 + r) * 4096 + j] = s[r] + bias;
  }
}

// ---------------- lstm_step2: 512 blocks; block owns dir d=bid>>8, units u0=(bid&255)*4.
// Wave w computes gate w for the 4 units. Whh pre-swizzled bf16; h in registers.
__global__ __launch_bounds__(256) void lstm_step2_kernel(
    const __hip_bfloat16* __restrict__ whh16s, const float* __restrict__ xg,
    float* __restrict__ hstate, float* __restrict__ cstate,
    float* __restrict__ hout, int s) {
  const int bid = blockIdx.x;
  const int d = bid >> 8, u0 = (bid & 255) * 4;
  const int tid = threadIdx.x, wave = tid >> 6, lane = tid & 63;
  const float* hread = hstate + ((size_t)(s & 1) * 2 + d) * 1024;
  float* hwrite = hstate + ((size_t)((s + 1) & 1) * 2 + d) * 1024;
  float* c = cstate + (size_t)d * 1024;
  const int r = d ? (7 - s) : s;

  float hreg[16];
  if (s == 0) {
#pragma unroll
    for (int cc = 0; cc < 16; ++cc) hreg[cc] = 0.f;
  } else {
#pragma unroll
    for (int cc = 0; cc < 16; ++cc) hreg[cc] = hread[cc * 64 + lane];
  }

  __shared__ float gsm[4][4];
#pragma unroll
  for (int ui = 0; ui < 4; ++ui) {
    int row = wave * 1024 + u0 + ui;
    const uint4* wp = (const uint4*)whh16s + ((size_t)d * 4096 + row) * 128 + lane;
    uint4 w0 = wp[0];
    uint4 w1 = wp[64];
    float sacc = 0.f;
#pragma unroll
    for (int e4 = 0; e4 < 4; ++e4) {
      uint32_t u = ((const uint32_t*)&w0)[e4];
      sacc += __uint_as_float(u << 16) * hreg[2 * e4] +
              __uint_as_float(u & 0xffff0000u) * hreg[2 * e4 + 1];
    }
#pragma unroll
    for (int e4 = 0; e4 < 4; ++e4) {
      uint32_t u = ((const uint32_t*)&w1)[e4];
      sacc += __uint_as_float(u << 16) * hreg[8 + 2 * e4] +
              __uint_as_float(u & 0xffff0000u) * hreg[8 + 2 * e4 + 1];
    }
#pragma unroll
    for (int off = 32; off; off >>= 1) sacc += __shfl_xor(sacc, off);
    if (lane == 0) gsm[wave][ui] = sacc;
  }
  __syncthreads();
  if (tid < 4) {
    int u = u0 + tid;
    const float* xgr = xg + ((size_t)d * 8 + r) * 4096;
    float gi = gsm[0][tid] + xgr[u];
    float gf = gsm[1][tid] + xgr[1024 + u];
    float gg = gsm[2][tid] + xgr[2048 + u];
    float go = gsm[3][tid] + xgr[3072 + u];
    float iv = 1.f / (1.f + __expf(-gi));
    float fv = 1.f / (1.f + __expf(-gf));
    float ov = 1.f / (1.f + __expf(-go));
    float cold = (s == 0) ? 0.f : c[u];
    float cn = fv * cold + iv * tanhf(gg);
    float hn = ov * tanhf(cn);
    c[u] = cn;
    hwrite[u] = hn;
    hout[((size_t)d * 8 + r) * 1024 + u] = hn;
  }
}

// ---------------- logits = lstm_out @ out_w.T + out_b ; softmax over 42 classes
__global__ __launch_bounds__(256) void final_kernel(
    const float* __restrict__ hout, const float* __restrict__ out_w,
    const float* __restrict__ out_b, float* __restrict__ outp) {
  __shared__ float lo[2048];
  __shared__ float logits[64];
  const int s = blockIdx.x, tid = threadIdx.x;
  for (int i = tid; i < 1024; i += 256) {
    lo[i] = hout[(size_t)s * 1024 + i];
    lo[1024 + i] = hout[(size_t)(8 + s) * 1024 + i];
  }
  __syncthreads();
  const int wave = tid >> 6, lane = tid & 63;
  for (int cls = wave; cls < 42; cls += 4) {
    const float4* wr = (const float4*)(out_w + (size_t)cls * 2048);
    const float4* xr = (const float4*)lo;
    float acc = 0.f;
#pragma unroll
    for (int t = 0; t < 8; ++t) {
      int k4 = lane + t * 64;
      float4 w = wr[k4];
      float4 x = xr[k4];
      acc += w.x * x.x + w.y * x.y + w.z * x.z + w.w * x.w;
    }
#pragma unroll
    for (int off = 32; off; off >>= 1) acc += __shfl_xor(acc, off);
    if (lane == 0) logits[cls] = acc + out_b[cls];
  }
  __syncthreads();
  if (tid == 0) {
    float mx = -1e30f;
    for (int c2 = 0; c2 < 42; ++c2) mx = fmaxf(mx, logits[c2]);
    float sum = 0.f;
    for (int c2 = 0; c2 < 42; ++c2) {
      float e = __expf(logits[c2] - mx);
      logits[c2] = e;
      sum += e;
    }
    float inv = 1.f / sum;
    for (int c2 = 0; c2 < 42; ++c2) outp[s * 42 + c2] = logits[c2] * inv;
  }
}

extern "C" void kernel_launch(void* const* d_in, const int* in_sizes, int n_in,
                              void* d_out, int out_size, void* d_ws, size_t ws_size,
                              hipStream_t stream) {
  const float* hidden     = (const float*)d_in[0];
  const int*   inds       = (const int*)d_in[1];
  const float* Wkey       = (const float*)d_in[2];
  const float* Wque       = (const float*)d_in[3];
  const float* Wval       = (const float*)d_in[4];
  const float* in_proj_w  = (const float*)d_in[5];
  const float* in_proj_b  = (const float*)d_in[6];
  const float* out_proj_w = (const float*)d_in[7];
  const float* out_proj_b = (const float*)d_in[8];
  const float* Wih_f      = (const float*)d_in[9];
  const float* Whh_f      = (const float*)d_in[10];
  const float* bih_f      = (const float*)d_in[11];
  const float* bhh_f      = (const float*)d_in[12];
  const float* Wih_b      = (const float*)d_in[13];
  const float* Whh_b      = (const float*)d_in[14];
  const float* bih_b      = (const float*)d_in[15];
  const float* bhh_b      = (const float*)d_in[16];
  const float* out_w      = (const float*)d_in[17];
  const float* out_b      = (const float*)d_in[18];
  float* out = (float*)d_out;

  float* ws = (float*)d_ws;
  float* cat      = ws;                    // 786432
  float* qkv2     = cat + 786432;          // 3*786432
  float* attn_out = qkv2 + 2359296;        // 786432
  float* avg      = attn_out + 786432;     // 12288
  float* xg       = avg + 12288;           // 65536
  float* hstate   = xg + 65536;            // 4096
  float* cstate   = hstate + 4096;         // 2048
  float* hout     = cstate + 2048;         // 16384
  __hip_bfloat16* b16 = (__hip_bfloat16*)(hout + 16384);
  __hip_bfloat16* cat16     = b16;                  // 786432
  __hip_bfloat16* Wt16      = cat16 + 786432;       // 3*1536*1536
  __hip_bfloat16* inproj16  = Wt16 + 7077888;       // 4608*1536
  __hip_bfloat16* outproj16 = inproj16 + 7077888;   // 1536*1536
  __hip_bfloat16* kqv1      = outproj16 + 2359296;  // 3*786432
  __hip_bfloat16* ob16      = kqv1 + 2359296;       // 786432
  __hip_bfloat16* whh16s    = ob16 + 786432;        // 2*4096*1024

  gather_kernel<<<512, 256, 0, stream>>>(hidden, inds, cat, cat16);
  transpose_cvt_kernel<<<dim3(48, 48, 3), 256, 0, stream>>>(Wkey, Wque, Wval, Wt16);
  prep_kernel<<<8704, 256, 0, stream>>>(in_proj_w, out_proj_w, Whh_f, Whh_b,
                                        inproj16, outproj16, whh16s);

  mfma_gemm<true, false><<<dim3(24, 8, 3), 256, 0, stream>>>(
      cat16, 0, Wt16, 1536L * 1536, nullptr, 0, kqv1, 786432);
  mfma_gemm<false, true><<<dim3(24, 8, 3), 256, 0, stream>>>(
      kqv1, 786432, inproj16, 1536L * 1536, in_proj_b, 1536, qkv2, 786432);

  attn_kernel<<<96, 256, 0, stream>>>(qkv2, qkv2 + 786432, qkv2 + 2 * 786432, ob16);

  mfma_gemm<false, true><<<dim3(24, 8, 1), 256, 0, stream>>>(
      ob16, 0, outproj16, 0, out_proj_b, 0, attn_out, 0);

  avg_kernel<<<48, 256, 0, stream>>>(attn_out, cat, avg);

  lstm_pre2_kernel<<<2048, 256, 0, stream>>>(avg, Wih_f, bih_f, bhh_f, Wih_b, bih_b, bhh_b, xg);

  for (int s = 0; s < 8; ++s)
    lstm_step2_kernel<<<512, 256, 0, stream>>>(whh16s, xg, hstate, cstate, hout, s);

  final_kernel<<<8, 256, 0, stream>>>(hout, out_w, out_b, out);
}